// Round 1
// 3415.794 us; speedup vs baseline: 1.0226x; 1.0226x over previous
//
#include <hip/hip_runtime.h>
#include <cstdint>

#define HDIM   1536
#define DIN    256
#define NSTEP  1008     // (T-1)*B = 63*16
#define NWG    256
#define TPB    384      // 6 waves; wave w owns unit g*6+w in BOTH layers
#define UPW    6
#define NREP   8        // exchange replicas

// Exchange: one u32 per hidden unit: bf16 value | tag<<16.
// Per replica (u32 units): [h0 par0: 1536][h0 par1: 1536][h1 par0: 1536][h1 par1: 1536]
// Producer phase p: h0(p) -> parity p&1, tag p+1 ; h1(p-1) -> parity (p+1)&1, tag p+1.
// Consumer phase n: h0(n-1) at parity (n+1)&1 tag n ; h1(n-2) at parity n&1 tag n.
#define REP_W     6144
#define H1_OFF    3072
#define WS_FLAG_W (NREP*REP_W)   // 49152

typedef uint32_t u32x2 __attribute__((ext_vector_type(2)));

__device__ __forceinline__ float bflo(uint32_t p){ union{uint32_t u; float f;} v; v.u = p << 16; return v.f; }
__device__ __forceinline__ float bfhi(uint32_t p){ union{uint32_t u; float f;} v; v.u = p & 0xffff0000u; return v.f; }
__device__ __forceinline__ float bf2f(uint16_t b){ union{uint32_t u; float f;} v; v.u = ((uint32_t)b) << 16; return v.f; }
__device__ __forceinline__ uint16_t f2bf(float f){
    union{float f; uint32_t u;} v; v.f = f;
    uint32_t r = v.u + 0x7fffu + ((v.u >> 16) & 1u);   // RNE
    return (uint16_t)(r >> 16);
}
__device__ __forceinline__ uint32_t packbf(float lo, float hi){
    return (uint32_t)f2bf(lo) | ((uint32_t)f2bf(hi) << 16);
}
// inf-safe fast tanh: 1 - 2/(e^{2x}+1)
__device__ __forceinline__ float tanh_fast(float x){
    return 1.f - 2.f/(__expf(2.f*x) + 1.f);
}

#if __has_builtin(__builtin_amdgcn_fdot2_f32_bf16)
typedef __bf16 bf16x2 __attribute__((ext_vector_type(2)));
__device__ __forceinline__ float dot2bf(uint32_t a, uint32_t b, float c){
    return __builtin_amdgcn_fdot2_f32_bf16(__builtin_bit_cast(bf16x2, a),
                                           __builtin_bit_cast(bf16x2, b), c, false);
}
#else
__device__ __forceinline__ float dot2bf(uint32_t a, uint32_t b, float c){
    c = fmaf(bflo(a), bflo(b), c);
    c = fmaf(bfhi(a), bfhi(b), c);
    return c;
}
#endif

__device__ __forceinline__ float wave_sum(float x){
    #pragma unroll
    for (int o = 1; o < 64; o <<= 1) x += __shfl_xor(x, o, 64);
    return x;
}

// Poll 12 tagged u64 (24 tagged u32 values) from per-lane address a.
// addr_k = a + 512*k - 2816 ; success when ALL hi16 tags == want (wave-uniform loop).
// On success pr[k] = pair (lo16 of word0 | lo16 of word1 << 16).
template<int SLOW>
__device__ __forceinline__ void poll12(const char* a, uint32_t want, uint32_t pr[12]){
    u32x2 q0,q1,q2,q3,q4,q5,q6,q7,q8,q9,qa,qb;
    const uint32_t want2 = want | (want << 16);
    int t = 0;
    for (;;){
        asm volatile(
            "global_load_dwordx2 %0,  %12, off offset:-2816 sc0 sc1\n\t"
            "global_load_dwordx2 %1,  %12, off offset:-2304 sc0 sc1\n\t"
            "global_load_dwordx2 %2,  %12, off offset:-1792 sc0 sc1\n\t"
            "global_load_dwordx2 %3,  %12, off offset:-1280 sc0 sc1\n\t"
            "global_load_dwordx2 %4,  %12, off offset:-768 sc0 sc1\n\t"
            "global_load_dwordx2 %5,  %12, off offset:-256 sc0 sc1\n\t"
            "global_load_dwordx2 %6,  %12, off offset:256 sc0 sc1\n\t"
            "global_load_dwordx2 %7,  %12, off offset:768 sc0 sc1\n\t"
            "global_load_dwordx2 %8,  %12, off offset:1280 sc0 sc1\n\t"
            "global_load_dwordx2 %9,  %12, off offset:1792 sc0 sc1\n\t"
            "global_load_dwordx2 %10, %12, off offset:2304 sc0 sc1\n\t"
            "global_load_dwordx2 %11, %12, off offset:2816 sc0 sc1\n\t"
            "s_waitcnt vmcnt(0)"
            : "=v"(q0),"=v"(q1),"=v"(q2),"=v"(q3),"=v"(q4),"=v"(q5),
              "=v"(q6),"=v"(q7),"=v"(q8),"=v"(q9),"=v"(qa),"=v"(qb)
            : "v"(a) : "memory");
        uint32_t d;
        d  = __builtin_amdgcn_perm(q0.y, q0.x, 0x07060302u) ^ want2;
        d |= __builtin_amdgcn_perm(q1.y, q1.x, 0x07060302u) ^ want2;
        d |= __builtin_amdgcn_perm(q2.y, q2.x, 0x07060302u) ^ want2;
        d |= __builtin_amdgcn_perm(q3.y, q3.x, 0x07060302u) ^ want2;
        d |= __builtin_amdgcn_perm(q4.y, q4.x, 0x07060302u) ^ want2;
        d |= __builtin_amdgcn_perm(q5.y, q5.x, 0x07060302u) ^ want2;
        d |= __builtin_amdgcn_perm(q6.y, q6.x, 0x07060302u) ^ want2;
        d |= __builtin_amdgcn_perm(q7.y, q7.x, 0x07060302u) ^ want2;
        d |= __builtin_amdgcn_perm(q8.y, q8.x, 0x07060302u) ^ want2;
        d |= __builtin_amdgcn_perm(q9.y, q9.x, 0x07060302u) ^ want2;
        d |= __builtin_amdgcn_perm(qa.y, qa.x, 0x07060302u) ^ want2;
        d |= __builtin_amdgcn_perm(qb.y, qb.x, 0x07060302u) ^ want2;
        if (__all(d == 0u)) break;
        if (SLOW){
            if (t == 0) __builtin_amdgcn_s_sleep(8);
            else        __builtin_amdgcn_s_sleep(2);
        } else {
            __builtin_amdgcn_s_sleep(2);
        }
        ++t;
    }
    pr[0]  = __builtin_amdgcn_perm(q0.y, q0.x, 0x05040100u);
    pr[1]  = __builtin_amdgcn_perm(q1.y, q1.x, 0x05040100u);
    pr[2]  = __builtin_amdgcn_perm(q2.y, q2.x, 0x05040100u);
    pr[3]  = __builtin_amdgcn_perm(q3.y, q3.x, 0x05040100u);
    pr[4]  = __builtin_amdgcn_perm(q4.y, q4.x, 0x05040100u);
    pr[5]  = __builtin_amdgcn_perm(q5.y, q5.x, 0x05040100u);
    pr[6]  = __builtin_amdgcn_perm(q6.y, q6.x, 0x05040100u);
    pr[7]  = __builtin_amdgcn_perm(q7.y, q7.x, 0x05040100u);
    pr[8]  = __builtin_amdgcn_perm(q8.y, q8.x, 0x05040100u);
    pr[9]  = __builtin_amdgcn_perm(q9.y, q9.x, 0x05040100u);
    pr[10] = __builtin_amdgcn_perm(qa.y, qa.x, 0x05040100u);
    pr[11] = __builtin_amdgcn_perm(qb.y, qb.x, 0x05040100u);
}

// ---------------------------------------------------------------------------
// init kernel: full clear of exchange region (kills stale tags from prior
// dispatch), seed h1 parity-1 boot tag, dtype probe.
// ---------------------------------------------------------------------------
__global__ void init_ws(const uint32_t* __restrict__ w, uint32_t* __restrict__ ws){
    const int i = blockIdx.x * blockDim.x + threadIdx.x;
    if (i < NREP*REP_W){
        const int j = i % REP_W;
        ws[i] = (j >= H1_OFF + 1536) ? 0x00010000u : 0u;   // h1(-1): tag 1, zeros
    }
    if (blockIdx.x == 0 && threadIdx.x < 64){
        const int t = threadIdx.x;
        int cnt = 0;
        #pragma unroll
        for (int j = 0; j < 4; ++j){
            const uint32_t v = w[t*4 + j];
            const uint32_t e = (v >> 7) & 0xFFu;
            if (e == 0u || (e >= 0x70u && e <= 0x7Cu)) cnt++;
        }
        #pragma unroll
        for (int o = 1; o < 64; o <<= 1) cnt += __shfl_xor(cnt, o, 64);
        if (t == 0)
            ws[WS_FLAG_W] = (cnt < 128) ? 1u : 0u;   // sparse in-window => fp32
    }
}

__global__ __launch_bounds__(TPB, 1)
void lstm_seq_kernel(const void* __restrict__ batch_,
                     const void* __restrict__ Wih0_,
                     const void* __restrict__ Whh0_,
                     const void* __restrict__ bih0_,
                     const void* __restrict__ bhh0_,
                     const void* __restrict__ Wih1_,
                     const void* __restrict__ Whh1_,
                     const void* __restrict__ bih1_,
                     const void* __restrict__ bhh1_,
                     void* __restrict__ out_,
                     uint32_t* __restrict__ ws)
{
    __shared__ uint32_t lds_w[UPW*4*8*64];   // L1 chunks 0..7 per owned row
    __shared__ uint32_t lds_h0[768];         // packed h0 pairs (wave0-written)
    __shared__ uint32_t lds_h1[768];         // packed h1 pairs (wave1-written)
    __shared__ int      lds_flag[2];

    const int g   = blockIdx.x;
    const int tid = threadIdx.x;
    const int w   = tid >> 6;        // wave 0..5
    const int l   = tid & 63;
    const int U   = g*UPW + w;       // owned hidden unit (both layers)

    const uint32_t fp32in = __hip_atomic_load(&ws[WS_FLAG_W],
                             __ATOMIC_RELAXED, __HIP_MEMORY_SCOPE_AGENT);

    if (tid < 2) lds_flag[tid] = -1;

    // ---------------- persistent weight load (once) ----------------
    uint32_t w0[4][14];   // L0 rows of unit U: 2 x-chunks + 12 h-chunks
    uint32_t w1[4][16];   // L1 rows: chunks 8..11 (W_ih1) + 12..23 (W_hh1)
    float bb0[4], bb1[4];

    if (fp32in){
        const float2* Wih0f = (const float2*)Wih0_;
        const float2* Whh0f = (const float2*)Whh0_;
        const float2* Wih1f = (const float2*)Wih1_;
        const float2* Whh1f = (const float2*)Whh1_;
        #pragma unroll
        for (int r = 0; r < 4; ++r){
            const int grow = r*HDIM + U;
            float2 t;
            t = Wih0f[grow*(DIN/2) + l];      w0[r][0] = packbf(t.x, t.y);
            t = Wih0f[grow*(DIN/2) + 64 + l]; w0[r][1] = packbf(t.x, t.y);
            #pragma unroll
            for (int c = 0; c < 12; ++c){
                t = Whh0f[grow*(HDIM/2) + c*64 + l]; w0[r][c+2] = packbf(t.x, t.y);
            }
            #pragma unroll
            for (int c = 0; c < 8; ++c){
                t = Wih1f[grow*(HDIM/2) + c*64 + l];
                lds_w[(w*4 + r)*512 + c*64 + l] = packbf(t.x, t.y);
            }
            #pragma unroll
            for (int c = 8; c < 12; ++c){
                t = Wih1f[grow*(HDIM/2) + c*64 + l]; w1[r][c-8] = packbf(t.x, t.y);
            }
            #pragma unroll
            for (int c = 0; c < 12; ++c){
                t = Whh1f[grow*(HDIM/2) + c*64 + l]; w1[r][c+4] = packbf(t.x, t.y);
            }
            bb0[r] = ((const float*)bih0_)[grow] + ((const float*)bhh0_)[grow];
            bb1[r] = ((const float*)bih1_)[grow] + ((const float*)bhh1_)[grow];
        }
    } else {
        const uint32_t* Wih0p = (const uint32_t*)Wih0_;
        const uint32_t* Whh0p = (const uint32_t*)Whh0_;
        const uint32_t* Wih1p = (const uint32_t*)Wih1_;
        const uint32_t* Whh1p = (const uint32_t*)Whh1_;
        #pragma unroll
        for (int r = 0; r < 4; ++r){
            const int grow = r*HDIM + U;
            w0[r][0] = Wih0p[grow*(DIN/2) + l];
            w0[r][1] = Wih0p[grow*(DIN/2) + 64 + l];
            #pragma unroll
            for (int c = 0; c < 12; ++c) w0[r][c+2] = Whh0p[grow*(HDIM/2) + c*64 + l];
            #pragma unroll
            for (int c = 0; c < 8; ++c)
                lds_w[(w*4 + r)*512 + c*64 + l] = Wih1p[grow*(HDIM/2) + c*64 + l];
            #pragma unroll
            for (int c = 8; c < 12; ++c) w1[r][c-8] = Wih1p[grow*(HDIM/2) + c*64 + l];
            #pragma unroll
            for (int c = 0; c < 12; ++c) w1[r][c+4] = Whh1p[grow*(HDIM/2) + c*64 + l];
            bb0[r] = bf2f(((const uint16_t*)bih0_)[grow]) + bf2f(((const uint16_t*)bhh0_)[grow]);
            bb1[r] = bf2f(((const uint16_t*)bih1_)[grow]) + bf2f(((const uint16_t*)bhh1_)[grow]);
        }
    }
    __syncthreads();   // lds_flag init only; no barriers in the main loop

    float c0 = 0.f, c1 = 0.f, h0f = 0.f, h1f = 0.f;
    uint32_t* wsrep = ws + (g & (NREP-1))*REP_W;

    for (int n = 0; n <= NSTEP; ++n){
        // x prefetch (issued before any spinning)
        uint32_t xp0 = 0, xp1 = 0;
        if (n < NSTEP){
            const int xbase = ((n & 15)*64 + (n >> 4) + 1) * DIN;
            if (fp32in){
                const float2* bp = (const float2*)((const float*)batch_ + xbase);
                const float2 t0 = bp[l];
                const float2 t1 = bp[64 + l];
                xp0 = packbf(t0.x, t0.y); xp1 = packbf(t1.x, t1.y);
            } else {
                const uint32_t* bp = (const uint32_t*)batch_ + (xbase >> 1);
                xp0 = bp[l]; xp1 = bp[64 + l];
            }
        }

        uint32_t h0p[12];
        uint32_t h1p[12];

        // wave 1: EARLY h1 ingest (h1(n-2) was published last phase; ~1 sweep)
        if (w == 1 && n >= 1){
            const char* a = (const char*)(wsrep + H1_OFF + (n & 1)*1536) + 8*l + 2816;
            poll12<0>(a, (uint32_t)n, h1p);
            #pragma unroll
            for (int k = 0; k < 12; ++k) lds_h1[k*64 + l] = h1p[k];
            __hip_atomic_store(&lds_flag[1], n, __ATOMIC_RELEASE, __HIP_MEMORY_SCOPE_WORKGROUP);
        }

        // h0 ingest: wave 0 polls LLC, others take LDS rebroadcast
        if (w == 0){
            const char* a = (const char*)(wsrep + ((n+1) & 1)*1536) + 8*l + 2816;
            poll12<1>(a, (uint32_t)n, h0p);
            #pragma unroll
            for (int k = 0; k < 12; ++k) lds_h0[k*64 + l] = h0p[k];
            __hip_atomic_store(&lds_flag[0], n, __ATOMIC_RELEASE, __HIP_MEMORY_SCOPE_WORKGROUP);
        } else {
            while (__hip_atomic_load(&lds_flag[0], __ATOMIC_ACQUIRE, __HIP_MEMORY_SCOPE_WORKGROUP) < n)
                __builtin_amdgcn_s_sleep(1);
            #pragma unroll
            for (int k = 0; k < 12; ++k) h0p[k] = lds_h0[k*64 + l];
        }

        // ---------------- layer 0 (the critical recurrence) ----------------
        if (n < NSTEP){
            __builtin_amdgcn_s_setprio(1);
            float acc[4];
            #pragma unroll
            for (int r = 0; r < 4; ++r){
                float a = dot2bf(w0[r][0], xp0, 0.f);
                a = dot2bf(w0[r][1], xp1, a);
                #pragma unroll
                for (int k = 0; k < 12; ++k) a = dot2bf(w0[r][k+2], h0p[k], a);
                acc[r] = a;
            }
            #pragma unroll
            for (int r = 0; r < 4; ++r) acc[r] = wave_sum(acc[r]);
            const float gi = acc[0] + bb0[0];
            const float gf = acc[1] + bb0[1];
            const float gg = acc[2] + bb0[2];
            const float go = acc[3] + bb0[3];
            const float si = 1.f/(1.f + __expf(-gi));
            const float sf = 1.f/(1.f + __expf(-gf));
            const float so = 1.f/(1.f + __expf(-go));
            c0  = sf*c0 + si*tanh_fast(gg);
            h0f = so*tanh_fast(c0);
            // publish h0(n) immediately: parity n&1, tag n+1, all replicas
            const uint32_t pk = (uint32_t)f2bf(h0f) | ((uint32_t)(n + 1) << 16);
            if (l < NREP)
                __hip_atomic_store(ws + l*REP_W + (n & 1)*1536 + U, pk,
                                   __ATOMIC_RELAXED, __HIP_MEMORY_SCOPE_AGENT);
            __builtin_amdgcn_s_setprio(0);
        }

        // ---------------- layer 1 (trails with a phase of slack) ----------------
        if (n >= 1){
            if (w != 1){
                while (__hip_atomic_load(&lds_flag[1], __ATOMIC_ACQUIRE, __HIP_MEMORY_SCOPE_WORKGROUP) < n)
                    __builtin_amdgcn_s_sleep(1);
                #pragma unroll
                for (int k = 0; k < 12; ++k) h1p[k] = lds_h1[k*64 + l];
            }
            float acc[4];
            #pragma unroll
            for (int r = 0; r < 4; ++r){
                float a = 0.f;
                #pragma unroll
                for (int c = 0; c < 8; ++c)
                    a = dot2bf(lds_w[(w*4 + r)*512 + c*64 + l], h0p[c], a);
                #pragma unroll
                for (int c = 8; c < 12; ++c) a = dot2bf(w1[r][c-8], h0p[c], a);
                #pragma unroll
                for (int k = 0; k < 12; ++k) a = dot2bf(w1[r][k+4], h1p[k], a);
                acc[r] = a;
            }
            #pragma unroll
            for (int r = 0; r < 4; ++r) acc[r] = wave_sum(acc[r]);
            const float gi = acc[0] + bb1[0];
            const float gf = acc[1] + bb1[1];
            const float gg = acc[2] + bb1[2];
            const float go = acc[3] + bb1[3];
            const float si = 1.f/(1.f + __expf(-gi));
            const float sf = 1.f/(1.f + __expf(-gf));
            const float so = 1.f/(1.f + __expf(-go));
            c1  = sf*c1 + si*tanh_fast(gg);
            h1f = so*tanh_fast(c1);
            if (n < NSTEP){
                const uint32_t pk = (uint32_t)f2bf(h1f) | ((uint32_t)(n + 1) << 16);
                if (l < NREP)
                    __hip_atomic_store(ws + l*REP_W + H1_OFF + ((n+1) & 1)*1536 + U, pk,
                                       __ATOMIC_RELAXED, __HIP_MEMORY_SCOPE_AGENT);
            }
        }
    }

    // ---------------- output: h[2][1536] ++ c[2][1536] ----------------
    if (l == 0){
        if (fp32in){
            float* o = (float*)out_;
            o[U]               = h0f;
            o[HDIM + U]        = h1f;
            o[3072 + U]        = c0;
            o[3072 + HDIM + U] = c1;
        } else {
            uint16_t* o = (uint16_t*)out_;
            o[U]               = f2bf(h0f);
            o[HDIM + U]        = f2bf(h1f);
            o[3072 + U]        = f2bf(c0);
            o[3072 + HDIM + U] = f2bf(c1);
        }
    }
}

extern "C" void kernel_launch(void* const* d_in, const int* in_sizes, int n_in,
                              void* d_out, int out_size, void* d_ws, size_t ws_size,
                              hipStream_t stream)
{
    (void)in_sizes; (void)n_in; (void)out_size; (void)ws_size;
    const void* batch = d_in[0];
    const void* Wih0  = d_in[1];
    const void* Whh0  = d_in[2];
    const void* bih0  = d_in[3];
    const void* bhh0  = d_in[4];
    const void* Wih1  = d_in[5];
    const void* Whh1  = d_in[6];
    const void* bih1  = d_in[7];
    const void* bhh1  = d_in[8];
    void* out = d_out;
    uint32_t* ws = (uint32_t*)d_ws;

    hipLaunchKernelGGL(init_ws, dim3((NREP*REP_W + 255)/256), dim3(256), 0, stream,
                       (const uint32_t*)Whh0, ws);

    void* args[] = { &batch, &Wih0, &Whh0, &bih0, &bhh0,
                     &Wih1, &Whh1, &bih1, &bhh1, &out, &ws };
    hipLaunchCooperativeKernel((const void*)lstm_seq_kernel,
                               dim3(NWG), dim3(TPB), args, 0, stream);
}